// Round 2
// baseline (295.420 us; speedup 1.0000x reference)
//
#include <hip/hip_runtime.h>
#include <hip/hip_bf16.h>

// B=2048, T=32, V=1024, D=256
// idx[b][t] = argmin_v (c2[t][v] - 2*x[b][t].c[t][v]);  embed = gathered codebook rows.
// R1 restructure: B tile per t is 512KB bf16 = L2-resident and shared by the 16
// co-XCD blocks of that t, so LDS-staging it was pure overhead (2-phase barrier
// drain, 128 barriers/block). Now: B fragments load global->reg directly with a
// 1-step register double-buffer; the kc loop has ZERO barriers. A (x-tile, 8x
// reuse) stays in LDS, staged once. Prep emits plain row-major bf16 codebook.

#define B_ 2048
#define T_ 32
#define V_ 1024
#define D_ 256
#define BT 128
#define VT 128
#define NVT 8
#define CAND_MAX 1280
#define MARGIN 8.0f

typedef __attribute__((ext_vector_type(8))) short short8;   // 8 bf16 = 4 VGPR
typedef __attribute__((ext_vector_type(4))) float f32x4;

__device__ __forceinline__ unsigned short f2bf(float f) {
    unsigned u = __builtin_bit_cast(unsigned, f);
    unsigned r = u + 0x7FFFu + ((u >> 16) & 1u);
    return (unsigned short)(r >> 16);
}

__device__ __forceinline__ short8 pack8(float4 a, float4 b) {
    short8 r;
    r[0] = (short)f2bf(a.x); r[1] = (short)f2bf(a.y);
    r[2] = (short)f2bf(a.z); r[3] = (short)f2bf(a.w);
    r[4] = (short)f2bf(b.x); r[5] = (short)f2bf(b.y);
    r[6] = (short)f2bf(b.z); r[7] = (short)f2bf(b.w);
    return r;
}

// ---- prep (fused): c2 exact fp32 + codebook -> plain row-major bf16
__global__ void prep_kernel(const float* __restrict__ cb, float* __restrict__ c2,
                            unsigned short* __restrict__ cbb) {
    const int wave = threadIdx.x >> 6, lane = threadIdx.x & 63;
    const int row = blockIdx.x * 4 + wave;                 // t*V + v
    const float4 v4 = *(const float4*)(cb + (size_t)row * D_ + lane * 4);
    float s = v4.x * v4.x + v4.y * v4.y + v4.z * v4.z + v4.w * v4.w;
    #pragma unroll
    for (int off = 32; off; off >>= 1) s += __shfl_down(s, off, 64);
    if (lane == 0) c2[row] = s;

    ushort4 b4;
    b4.x = f2bf(v4.x); b4.y = f2bf(v4.y); b4.z = f2bf(v4.z); b4.w = f2bf(v4.w);
    *(ushort4*)(cbb + (size_t)row * D_ + lane * 4) = b4;
}

// ---- fallback prep when ws too small: c2 only
__global__ void c2_kernel(const float* __restrict__ cb, float* __restrict__ c2) {
    const int row = blockIdx.x * 4 + (threadIdx.x >> 6);
    const int lane = threadIdx.x & 63;
    const float4 v = ((const float4*)(cb + (size_t)row * D_))[lane];
    float s = v.x * v.x + v.y * v.y + v.z * v.z + v.w * v.w;
    #pragma unroll
    for (int off = 32; off; off >>= 1) s += __shfl_down(s, off, 64);
    if (lane == 0) c2[row] = s;
}

// ---------------- main ----------------
__global__ __launch_bounds__(256, 2)
void vq_kernel(const float* __restrict__ x, const float* __restrict__ cb,
               const float* __restrict__ c2, const unsigned short* __restrict__ cbb,
               float* __restrict__ out, int use_bf) {
    const int t  = blockIdx.x;
    const int b0 = blockIdx.y * BT;

    // LDS = 65536 + 1024 + 1024 + 5120 + 4 = 72,708 B  -> 2 blocks/CU
    __shared__ short8 A_lds[4096];            // 128 rows x 32 granules, XOR(r&15)
    __shared__ float  minPart[BT * 2];        // cumulative row-min per wn half
    __shared__ unsigned long long result[BT];
    __shared__ unsigned s_cand[CAND_MAX];
    __shared__ unsigned s_cnt;

    const int tid = threadIdx.x;
    const int wave = tid >> 6, lane = tid & 63;
    const int wm = wave & 1, wn = wave >> 1;
    const int q = lane >> 4, ln = lane & 15;

    if (tid < BT) result[tid] = ~0ULL;
    minPart[tid] = 3.4e38f;
    if (tid == 0) s_cnt = 0;

    // stage A once (fp32 -> bf16, XOR swizzle; once per block so VALU cost ok)
    #pragma unroll
    for (int i = 0; i < 16; ++i) {
        int gid = i * 256 + tid, r = gid >> 5, g = gid & 31;
        const float4* src = (const float4*)(x + (((size_t)(b0 + r)) * T_ + t) * D_ + g * 8);
        A_lds[r * 32 + (g ^ (r & 15))] = pack8(src[0], src[1]);
    }

    // B direct-load lane bases: lane (q,ln) of wave wn owns row wn*64+nt*16+ln,
    // k-granule q of the current kc chunk (16B, one 64B line per 4 q-lanes).
    const unsigned short* bb = cbb + ((size_t)t * V_ + wn * 64 + ln) * D_ + q * 8;
    const float*          fb = cb  + ((size_t)t * V_ + wn * 64 + ln) * D_ + q * 8;

    auto loadB = [&](int vt, int kc, short8 (&dst)[4]) {
        #pragma unroll
        for (int nt = 0; nt < 4; ++nt) {
            const int off = (vt * VT + nt * 16) * D_ + kc * 32;
            if (use_bf) {
                dst[nt] = *(const short8*)(bb + off);
            } else {
                const float4* s = (const float4*)(fb + off);
                dst[nt] = pack8(s[0], s[1]);
            }
        }
    };

    short8 bA[4], bB[4];
    loadB(0, 0, bA);                 // overlaps with A staging (reg loads)
    __syncthreads();                 // A_lds writes landed

    const int abase = (wm * 64 + ln) * 32;

    for (int vt = 0; vt < NVT; ++vt) {
        f32x4 acc[4][4];
        #pragma unroll
        for (int mt = 0; mt < 4; ++mt)
            #pragma unroll
            for (int nt = 0; nt < 4; ++nt) acc[mt][nt] = (f32x4){0.f, 0.f, 0.f, 0.f};

        #pragma unroll
        for (int kh = 0; kh < 4; ++kh) {
            const int kc0 = kh * 2, kc1 = kh * 2 + 1;

            loadB(vt, kc1, bB);      // prefetch next half-step
            {
                short8 af[4];
                #pragma unroll
                for (int mt = 0; mt < 4; ++mt)
                    af[mt] = A_lds[abase + mt * 512 + ((kc0 * 4 + q) ^ ln)];
                #pragma unroll
                for (int mt = 0; mt < 4; ++mt)
                    #pragma unroll
                    for (int nt = 0; nt < 4; ++nt)
                        acc[mt][nt] = __builtin_amdgcn_mfma_f32_16x16x32_bf16(af[mt], bA[nt], acc[mt][nt], 0, 0, 0);
            }
            if (!(vt == NVT - 1 && kh == 3)) {
                int nv = vt, nk = kc0 + 2;
                if (kh == 3) { nv = vt + 1; nk = 0; }
                loadB(nv, nk, bA);   // prefetch next (crosses epilogue at vt end)
            }
            {
                short8 af[4];
                #pragma unroll
                for (int mt = 0; mt < 4; ++mt)
                    af[mt] = A_lds[abase + mt * 512 + ((kc1 * 4 + q) ^ ln)];
                #pragma unroll
                for (int mt = 0; mt < 4; ++mt)
                    #pragma unroll
                    for (int nt = 0; nt < 4; ++nt)
                        acc[mt][nt] = __builtin_amdgcn_mfma_f32_16x16x32_bf16(af[mt], bB[nt], acc[mt][nt], 0, 0, 0);
            }
        }

        // ---- epilogue: update shared running row-min, then collect candidates
        const float* c2p = c2 + t * V_ + vt * VT + wn * 64 + ln;
        float cc[4];
        #pragma unroll
        for (int nt = 0; nt < 4; ++nt) cc[nt] = c2p[nt * 16];

        #pragma unroll
        for (int mt = 0; mt < 4; ++mt)
            #pragma unroll
            for (int i = 0; i < 4; ++i) {
                float mn = 3.4e38f;
                #pragma unroll
                for (int nt = 0; nt < 4; ++nt)
                    mn = fminf(mn, fmaf(-2.0f, acc[mt][nt][i], cc[nt]));
                mn = fminf(mn, __shfl_xor(mn, 1, 64));
                mn = fminf(mn, __shfl_xor(mn, 2, 64));
                mn = fminf(mn, __shfl_xor(mn, 4, 64));
                mn = fminf(mn, __shfl_xor(mn, 8, 64));
                if (ln == 0) {
                    int r = wm * 64 + mt * 16 + q * 4 + i;
                    minPart[r * 2 + wn] = fminf(minPart[r * 2 + wn], mn);
                }
            }
        __syncthreads();

        #pragma unroll
        for (int mt = 0; mt < 4; ++mt)
            #pragma unroll
            for (int i = 0; i < 4; ++i) {
                int r = wm * 64 + mt * 16 + q * 4 + i;
                float2 mp = *(const float2*)&minPart[r * 2];
                float thr = fminf(mp.x, mp.y) + MARGIN;
                #pragma unroll
                for (int nt = 0; nt < 4; ++nt) {
                    float s = fmaf(-2.0f, acc[mt][nt][i], cc[nt]);
                    if (s < thr) {
                        int v = vt * VT + wn * 64 + nt * 16 + ln;
                        unsigned pos = atomicAdd(&s_cnt, 1u);
                        if (pos < CAND_MAX) s_cand[pos] = (unsigned)((r << 10) | v);
                    }
                }
            }
        // no barrier needed: minPart is monotone-decreasing and per-(r,wn) cell
        // single-writer; the per-vt __syncthreads above bounds wave drift.
    }

    // ---- exact fp32 rescore of candidates (16-lane groups)
    __syncthreads();
    const unsigned ncand = min(s_cnt, (unsigned)CAND_MAX);
    const int grp = tid >> 4, l16 = tid & 15;
    for (unsigned ci = grp; ci < ncand; ci += 16) {
        const unsigned e = s_cand[ci];
        const int row = e >> 10, v = e & 1023;
        const float* xr = x + (((size_t)(b0 + row)) * T_ + t) * D_ + l16 * 16;
        const float* cr = cb + ((size_t)t * V_ + v) * D_ + l16 * 16;
        float dot = 0.f;
        #pragma unroll
        for (int j = 0; j < 4; ++j) {
            float4 a = *(const float4*)(xr + j * 4);
            float4 b = *(const float4*)(cr + j * 4);
            dot = fmaf(a.x, b.x, dot); dot = fmaf(a.y, b.y, dot);
            dot = fmaf(a.z, b.z, dot); dot = fmaf(a.w, b.w, dot);
        }
        dot += __shfl_xor(dot, 1, 64);
        dot += __shfl_xor(dot, 2, 64);
        dot += __shfl_xor(dot, 4, 64);
        dot += __shfl_xor(dot, 8, 64);
        if (l16 == 0) {
            float sc = fmaf(-2.0f, dot, c2[t * V_ + v]);
            unsigned u = __builtin_bit_cast(unsigned, sc);
            u = (u & 0x80000000u) ? ~u : (u | 0x80000000u);   // sortable fp32
            atomicMin(&result[row], ((unsigned long long)u << 32) | (unsigned)v);
        }
    }
    __syncthreads();

    if (tid < BT)
        out[(size_t)B_ * T_ * D_ + (size_t)(b0 + tid) * T_ + t] =
            (float)(int)(result[tid] & 1023u);

    // ---- fused gather
    const int w = tid >> 6, gl = tid & 63;
    #pragma unroll
    for (int i = 0; i < 32; ++i) {
        const int row = w * 32 + i;
        const int idx = (int)(result[row] & 1023u);
        const float4 src = *(const float4*)(cb + ((size_t)t * V_ + idx) * D_ + gl * 4);
        *(float4*)(out + (((size_t)(b0 + row)) * T_ + t) * D_ + gl * 4) = src;
    }
}

extern "C" void kernel_launch(void* const* d_in, const int* in_sizes, int n_in,
                              void* d_out, int out_size, void* d_ws, size_t ws_size,
                              hipStream_t stream) {
    const float* x  = (const float*)d_in[0];   // (B,T,D)
    const float* cb = (const float*)d_in[1];   // (T,V,D)
    float* out = (float*)d_out;                // embed fp32 ++ idx (as float)
    float* c2  = (float*)d_ws;                 // 32768 floats = 128 KB
    unsigned short* cbb = (unsigned short*)((char*)d_ws + 131072);  // 16 MB bf16 codebook
    const size_t NEED = 131072 + (size_t)T_ * V_ * D_ * 2;
    const int use_bf = (ws_size >= NEED) ? 1 : 0;

    if (use_bf) prep_kernel<<<dim3(T_ * V_ / 4), 256, 0, stream>>>(cb, c2, cbb);
    else        c2_kernel<<<dim3(T_ * V_ / 4), 256, 0, stream>>>(cb, c2);
    vq_kernel<<<dim3(T_, B_ / BT), 256, 0, stream>>>(x, cb, c2, cbb, out, use_bf);
}